// Round 6
// baseline (137.475 us; speedup 1.0000x reference)
//
#include <hip/hip_runtime.h>
#include <hip/hip_bf16.h>
#include <math.h>

#define B    4
#define QL   2048
#define KVL  2048
#define CQ   256
#define CKV  256
#define CH   32
#define NH   8
#define DM   256   // NH*CH
#define QB   128   // q rows per fattn block (8 waves x 16)
#define KVB  128   // kv strip per iteration

typedef __attribute__((ext_vector_type(8))) short short8;   // 8 x bf16 (4 VGPR)
typedef __attribute__((ext_vector_type(4))) short short4v;  // 4 x bf16 (2 VGPR)
typedef __attribute__((ext_vector_type(4))) float f32x4;

static __device__ __forceinline__ short f2bf(float x) {
    __hip_bfloat16 h = __float2bfloat16(x);
    return __builtin_bit_cast(short, h);
}

// ---------------------------------------------------------------------------
// prep: fp32 -> bf16 copy (8 elems/thread)
// ---------------------------------------------------------------------------
__global__ __launch_bounds__(256) void prep_cvt(
    const float* __restrict__ src, short* __restrict__ dst, int n8)
{
    int i = blockIdx.x * 256 + threadIdx.x;
    if (i >= n8) return;
    const float4* s = (const float4*)src + (size_t)i * 2;
    float4 a = s[0], b = s[1];
    short8 o = { f2bf(a.x), f2bf(a.y), f2bf(a.z), f2bf(a.w),
                 f2bf(b.x), f2bf(b.y), f2bf(b.z), f2bf(b.w) };
    *((short8*)dst + i) = o;
}

// ---------------------------------------------------------------------------
// prep: W [K][N] fp32 -> W^T [N][K] bf16, 32x32 LDS tiles
// ---------------------------------------------------------------------------
__global__ __launch_bounds__(256) void prep_wT(
    const float* __restrict__ w, short* __restrict__ wt, int K, int N)
{
    __shared__ float tile[32][33];
    const int bx = blockIdx.x * 32;            // n
    const int by = blockIdx.y * 32;            // k
    const int tx = threadIdx.x & 31, ty = threadIdx.x >> 5;
    #pragma unroll
    for (int i = 0; i < 32; i += 8)
        tile[ty + i][tx] = w[(size_t)(by + ty + i) * N + bx + tx];
    __syncthreads();
    #pragma unroll
    for (int i = 0; i < 32; i += 8)
        wt[(size_t)(bx + ty + i) * K + by + tx] = f2bf(tile[tx][ty + i]);
}

// ---------------------------------------------------------------------------
// bf16 MFMA GEMM (unchanged): A [M][K] bf16, BT [N][K] bf16.
// 64x64 tile, 4 waves (2x2 of 32x32), BK=32.
// ---------------------------------------------------------------------------
__global__ __launch_bounds__(256) void gemm_mfma(
    const short* __restrict__ A, const short* __restrict__ BT,
    const float* __restrict__ bias, float* __restrict__ outf,
    short* __restrict__ outb,
    int M, int N, int K, float alpha, int mode)
{
    __shared__ __align__(16) short As[64][40];
    __shared__ __align__(16) short Bs[64][40];

    const int t   = threadIdx.x;
    const int m0  = blockIdx.y * 64, n0 = blockIdx.x * 64;
    const int lane = t & 63, w = t >> 6;
    const int c16 = lane & 15, g = lane >> 4;
    const int wm  = (w & 1) * 32, wn = (w >> 1) * 32;
    const int lr  = t >> 2, lc = (t & 3) * 8;

    f32x4 acc[2][2] = {};

    for (int k0 = 0; k0 < K; k0 += 32) {
        __syncthreads();
        *(short8*)&As[lr][lc] = *(const short8*)(A  + (size_t)(m0 + lr) * K + k0 + lc);
        *(short8*)&Bs[lr][lc] = *(const short8*)(BT + (size_t)(n0 + lr) * K + k0 + lc);
        __syncthreads();

        short8 af[2], bf[2];
        #pragma unroll
        for (int i = 0; i < 2; i++) {
            af[i] = *(const short8*)&As[wm + i * 16 + c16][g * 8];
            bf[i] = *(const short8*)&Bs[wn + i * 16 + c16][g * 8];
        }
        #pragma unroll
        for (int i = 0; i < 2; i++)
            #pragma unroll
            for (int j = 0; j < 2; j++)
                acc[i][j] = __builtin_amdgcn_mfma_f32_16x16x32_bf16(af[i], bf[j], acc[i][j], 0, 0, 0);
    }

    #pragma unroll
    for (int i = 0; i < 2; i++) {
        #pragma unroll
        for (int j = 0; j < 2; j++) {
            #pragma unroll
            for (int r = 0; r < 4; r++) {
                int m = m0 + wm + i * 16 + g * 4 + r;
                int n = n0 + wn + j * 16 + c16;
                float v = acc[i][j][r] * alpha;
                if (mode == 0) {
                    outf[(size_t)m * N + n] = v + (bias ? bias[n] : 0.0f);
                } else {
                    int bb = m >> 11, l = m & 2047;
                    int hh = n >> 5,  cc = n & 31;
                    if (mode == 1)
                        outb[(((size_t)bb * NH + hh) * QL + l) * CH + cc] = f2bf(v);
                    else
                        outb[(((size_t)bb * NH + hh) * CH + cc) * (size_t)KVL + l] = f2bf(v);
                }
            }
        }
    }
}

// ---------------------------------------------------------------------------
// Flash attention, R6: swapped-operand QK^T (S^T fragment => per-lane
// kv-contiguous scores). Bias: 8x float4 loads. Mask: staged once to LDS.
// P-writes: 8x ds_write_b64. Static-max exp2 softmax (log2e in Q scale).
// Double-buffered K/V, one barrier per strip.
// Fragment maps (m89-derived):
//   A-frag lane: A[m=lane&15][k=(lane>>4)*8+j]
//   B-frag lane: B[k=(lane>>4)*8+j][n=lane&15]
//   D-frag lane reg r: D[row=(lane>>4)*4+r][col=lane&15]
// QK^T swapped: D = K·Q^T => lane (c16,g) reg r = S[q=c16][kv=16tt+4g+r].
// ---------------------------------------------------------------------------
__global__ __launch_bounds__(512) void fattn(
    const short* __restrict__ qbf, const short* __restrict__ kbf,
    const short* __restrict__ vtb, const float* __restrict__ mask,
    const float* __restrict__ bias, short* __restrict__ aob)
{
    __shared__ __align__(16) short Kl[2][KVB * 32];   // 16 KB, swizzled
    __shared__ __align__(16) short Vl[2][32 * KVB];   // 16 KB, swizzled (V^T)
    __shared__ __align__(16) short Pl[8][16 * KVB];   // 32 KB, per-wave, swizzled
    __shared__ __align__(16) float Ml[KVL];           // 8 KB, mask terms

    const int t    = threadIdx.x;
    const int w    = t >> 6;
    const int lane = t & 63;
    const int c16  = lane & 15;
    const int g    = lane >> 4;

    const int q0 = blockIdx.x * QB;
    const int h  = blockIdx.y, b = blockIdx.z;
    const int bh = b * NH + h;

    constexpr float L2E  = 1.4426950408889634f;
    constexpr float MBIG = 1e9f * L2E;                  // mask slope * log2e
    constexpr float MOFF = -(1e9f * L2E) - 40.0f * L2E; // -MBIG - C (static max, exp2 units)

    // per-thread staging addresses (K: [128 kv][32 ch], V^T: [32 ch][128 kv])
    const short* ksrc = kbf + (size_t)bh * KVL * CH + (t >> 2) * CH + (t & 3) * 8;
    const short* vsrc = vtb + (size_t)bh * CH * KVL + (t >> 4) * KVL + (t & 15) * 8;
    const int krow = t >> 2,  kch = t & 3;
    const int kbyte = (krow * 64 + kch * 16) ^ ((krow & 7) << 4);
    const int vrow = t >> 4,  vch = t & 15;
    const int vbyte = (vrow * 256 + vch * 16) ^ ((vrow & 7) << 4);

    short8 kreg = *(const short8*)ksrc;     // prefetch strip 0
    short8 vreg = *(const short8*)vsrc;

    // Q fragment: row q0 + w*16 + c16 (scale * log2e folded in projection)
    short8 qf = *(const short8*)(qbf + ((size_t)bh * QL + q0 + w * 16 + c16) * CH + g * 8);

    // mask terms -> LDS once per block (independent of q, h)
    {
        float4 mv = *(const float4*)(mask + (size_t)b * KVL + t * 4);
        float4 ml = { fmaf(mv.x, MBIG, MOFF), fmaf(mv.y, MBIG, MOFF),
                      fmaf(mv.z, MBIG, MOFF), fmaf(mv.w, MBIG, MOFF) };
        *(float4*)&Ml[t * 4] = ml;
    }

    f32x4 o0 = {0.f, 0.f, 0.f, 0.f}, o1 = {0.f, 0.f, 0.f, 0.f};
    float l0 = 0.f, l1 = 0.f, l2 = 0.f, l3 = 0.f;

    // bias row for this lane's q-row (swapped layout: row = c16)
    const float* brow = bias + ((size_t)h * QL + q0 + w * 16 + c16) * KVL;

    short* pw = &Pl[w][0];
    const f32x4 zero4 = {0.f, 0.f, 0.f, 0.f};

    #pragma unroll 1
    for (int it = 0; it < KVL / KVB; ++it) {
        const int kv0 = it * KVB;
        char* klb = (char*)Kl[it & 1];
        char* vlb = (char*)Vl[it & 1];

        // ---- bias prefetch: 8 x float4 (cols kv0+16tt+4g .. +3 of row c16) ----
        float4 bi4[8];
        #pragma unroll
        for (int tt = 0; tt < 8; ++tt)
            bi4[tt] = *(const float4*)(brow + kv0 + tt * 16 + 4 * g);

        // ---- stage prefetched K/V registers -> LDS, one barrier ----
        *(short8*)(klb + kbyte) = kreg;
        *(short8*)(vlb + vbyte) = vreg;
        __syncthreads();   // also covers Ml on first iteration

        // ---- issue next strip's global loads (overlap with compute) ----
        if (it + 1 < KVL / KVB) {
            kreg = *(const short8*)(ksrc + (size_t)(it + 1) * KVB * CH);
            vreg = *(const short8*)(vsrc + (it + 1) * KVB);
        }

        // ---- mask terms from LDS (broadcast reads) ----
        float4 mt4[8];
        #pragma unroll
        for (int tt = 0; tt < 8; ++tt)
            mt4[tt] = *(const float4*)&Ml[kv0 + tt * 16 + 4 * g];

        // ---- QK^T swapped: s[tt] = K-subtile x Q^T  (S^T fragments) ----
        f32x4 s[8];
        __builtin_amdgcn_s_setprio(1);
        #pragma unroll
        for (int tt = 0; tt < 8; ++tt) {
            int row  = tt * 16 + c16;
            int byte = (row * 64 + g * 16) ^ ((row & 7) << 4);
            short8 kf = *(const short8*)(klb + byte);
            s[tt] = __builtin_amdgcn_mfma_f32_16x16x32_bf16(kf, qf, zero4, 0, 0, 0);
        }
        __builtin_amdgcn_s_setprio(0);

        // ---- p = exp2(s + bias*log2e + mt); lane-local row partials;
        //      pack 4 bf16 -> one ds_write_b64 per tt ----
        #pragma unroll
        for (int tt = 0; tt < 8; ++tt) {
            float p0 = __builtin_amdgcn_exp2f(fmaf(bi4[tt].x, L2E, s[tt][0] + mt4[tt].x));
            float p1 = __builtin_amdgcn_exp2f(fmaf(bi4[tt].y, L2E, s[tt][1] + mt4[tt].y));
            float p2 = __builtin_amdgcn_exp2f(fmaf(bi4[tt].z, L2E, s[tt][2] + mt4[tt].z));
            float p3 = __builtin_amdgcn_exp2f(fmaf(bi4[tt].w, L2E, s[tt][3] + mt4[tt].w));
            l0 += p0; l1 += p1; l2 += p2; l3 += p3;
            short4v pk = { f2bf(p0), f2bf(p1), f2bf(p2), f2bf(p3) };
            int byte = (c16 * 256 + tt * 32 + g * 8) ^ ((c16 & 7) << 4);
            *(short4v*)((char*)pw + byte) = pk;
        }

        // same-wave cross-lane LDS write->read: explicit ordering (rule #18)
        asm volatile("s_waitcnt lgkmcnt(0)" ::: "memory");
        __builtin_amdgcn_sched_barrier(0);

        // ---- PV: O[16q][32c] += P[16][128] @ V[128][32] (unchanged) ----
        __builtin_amdgcn_s_setprio(1);
        #pragma unroll
        for (int kk = 0; kk < 4; ++kk) {
            int cb = (kk * 32 + g * 8) * 2;
            int pb  = (c16 * 256 + cb) ^ ((c16 & 7) << 4);
            short8 pf  = *(const short8*)((const char*)pw + pb);
            short8 vf0 = *(const short8*)(vlb + ((c16 * 256 + cb) ^ ((c16 & 7) << 4)));
            short8 vf1 = *(const short8*)(vlb + (((16 + c16) * 256 + cb) ^ ((c16 & 7) << 4)));
            o0 = __builtin_amdgcn_mfma_f32_16x16x32_bf16(pf, vf0, o0, 0, 0, 0);
            o1 = __builtin_amdgcn_mfma_f32_16x16x32_bf16(pf, vf1, o1, 0, 0, 0);
        }
        __builtin_amdgcn_s_setprio(0);
    }

    // ---- finalize: lane holds partial row-sum of q-row c16; reduce over the
    //      4 g-groups (lanes xor 16, 32), then redistribute to O-frag rows ----
    float lsum = (l0 + l1) + (l2 + l3);
    lsum += __shfl_xor(lsum, 16);
    lsum += __shfl_xor(lsum, 32);
    // O-frag: o0[r] = O[q=4g+r][ch=c16]; need 1/l for q-row 4g+r (held @ lane c16=4g+r)
    short* aop = aob + ((size_t)b * QL + q0 + w * 16) * DM + h * CH;
    #pragma unroll
    for (int r = 0; r < 4; r++) {
        float inv = 1.0f / __shfl(lsum, 4 * g + r);
        int q = 4 * g + r;
        aop[(size_t)q * DM + c16]      = f2bf(o0[r] * inv);
        aop[(size_t)q * DM + 16 + c16] = f2bf(o1[r] * inv);
    }
}

// ---------------------------------------------------------------------------
extern "C" void kernel_launch(void* const* d_in, const int* in_sizes, int n_in,
                              void* d_out, int out_size, void* d_ws, size_t ws_size,
                              hipStream_t stream)
{
    const float* input_q  = (const float*)d_in[0];
    const float* input_kv = (const float*)d_in[1];
    const float* mask     = (const float*)d_in[2];
    const float* bias     = (const float*)d_in[3];
    const float* w_q      = (const float*)d_in[4];
    const float* w_k      = (const float*)d_in[5];
    const float* w_v      = (const float*)d_in[6];
    const float* w_o      = (const float*)d_in[7];
    const float* b_o      = (const float*)d_in[8];
    float* out = (float*)d_out;

    const size_t TOK  = (size_t)B * QL;            // 8192
    const size_t HEAD = (size_t)B * NH * QL * CH;  // 2,097,152 elems

    short* qbf = (short*)d_ws;          // bf16 Q  head-split       4 MB
    short* kbf = qbf + HEAD;            // bf16 K  head-split       4 MB
    short* vtb = kbf + HEAD;            // bf16 V^T head-split      4 MB
    short* aob = vtb + HEAD;            // bf16 attn out [tok][dm]  4 MB
    short* qx  = aob + HEAD;            // bf16 input_q             4 MB
    short* kvx = qx  + HEAD;            // bf16 input_kv            4 MB
    short* wqT = kvx + HEAD;            // bf16 w_q^T  [N][K]       128 KB
    short* wkT = wqT + CQ * DM;
    short* wvT = wkT + CKV * DM;
    short* woT = wvT + CKV * DM;

    dim3 blk(256);
    // 1/sqrt(32) * log2(e): static-max softmax works in exp2 units
    const float qscale = 0.17677669529663687f * 1.4426950408889634f;

    prep_cvt<<<dim3((TOK * CQ / 8 + 255) / 256), blk, 0, stream>>>(input_q,  qx,  (int)(TOK * CQ / 8));
    prep_cvt<<<dim3((TOK * CKV / 8 + 255) / 256), blk, 0, stream>>>(input_kv, kvx, (int)(TOK * CKV / 8));
    prep_wT<<<dim3(DM / 32, CQ / 32),  blk, 0, stream>>>(w_q, wqT, CQ,  DM);
    prep_wT<<<dim3(DM / 32, CKV / 32), blk, 0, stream>>>(w_k, wkT, CKV, DM);
    prep_wT<<<dim3(DM / 32, CKV / 32), blk, 0, stream>>>(w_v, wvT, CKV, DM);
    prep_wT<<<dim3(CQ / 32, DM / 32),  blk, 0, stream>>>(w_o, woT, DM,  CQ);

    dim3 pgrid(DM / 64, TOK / 64);                 // (4, 128)
    gemm_mfma<<<pgrid, blk, 0, stream>>>(qx,  wqT, nullptr, nullptr, qbf,
                                         (int)TOK, DM, CQ,  qscale, 1);
    gemm_mfma<<<pgrid, blk, 0, stream>>>(kvx, wkT, nullptr, nullptr, kbf,
                                         (int)TOK, DM, CKV, 1.0f, 1);
    gemm_mfma<<<pgrid, blk, 0, stream>>>(kvx, wvT, nullptr, nullptr, vtb,
                                         (int)TOK, DM, CKV, 1.0f, 2);

    fattn<<<dim3(QL / QB, NH, B), dim3(512), 0, stream>>>(qbf, kbf, vtb, mask, bias, aob);

    gemm_mfma<<<dim3(CQ / 64, TOK / 64), blk, 0, stream>>>(aob, woT, b_o, out, nullptr,
                                         (int)TOK, CQ, DM, 1.0f, 0);
}

// Round 7
// 131.097 us; speedup vs baseline: 1.0486x; 1.0486x over previous
//
#include <hip/hip_runtime.h>
#include <hip/hip_bf16.h>
#include <math.h>

#define B    4
#define QL   2048
#define KVL  2048
#define CQ   256
#define CKV  256
#define CH   32
#define NH   8
#define DM   256   // NH*CH
#define QB   128   // q rows per fattn block (8 waves x 16)
#define KVB  128   // kv strip per iteration
#define NSTRIP (KVL / KVB)   // 16

typedef __attribute__((ext_vector_type(8))) short short8;   // 8 x bf16 (4 VGPR)
typedef __attribute__((ext_vector_type(4))) short short4v;  // 4 x bf16 (2 VGPR)
typedef __attribute__((ext_vector_type(4))) float f32x4;

static __device__ __forceinline__ short f2bf(float x) {
    __hip_bfloat16 h = __float2bfloat16(x);
    return __builtin_bit_cast(short, h);
}

// ---------------------------------------------------------------------------
// prep: fp32 -> bf16 copy (8 elems/thread)
// ---------------------------------------------------------------------------
__global__ __launch_bounds__(256) void prep_cvt(
    const float* __restrict__ src, short* __restrict__ dst, int n8)
{
    int i = blockIdx.x * 256 + threadIdx.x;
    if (i >= n8) return;
    const float4* s = (const float4*)src + (size_t)i * 2;
    float4 a = s[0], b = s[1];
    short8 o = { f2bf(a.x), f2bf(a.y), f2bf(a.z), f2bf(a.w),
                 f2bf(b.x), f2bf(b.y), f2bf(b.z), f2bf(b.w) };
    *((short8*)dst + i) = o;
}

// ---------------------------------------------------------------------------
// prep: W [K][N] fp32 -> W^T [N][K] bf16, 32x32 LDS tiles
// ---------------------------------------------------------------------------
__global__ __launch_bounds__(256) void prep_wT(
    const float* __restrict__ w, short* __restrict__ wt, int K, int N)
{
    __shared__ float tile[32][33];
    const int bx = blockIdx.x * 32;            // n
    const int by = blockIdx.y * 32;            // k
    const int tx = threadIdx.x & 31, ty = threadIdx.x >> 5;
    #pragma unroll
    for (int i = 0; i < 32; i += 8)
        tile[ty + i][tx] = w[(size_t)(by + ty + i) * N + bx + tx];
    __syncthreads();
    #pragma unroll
    for (int i = 0; i < 32; i += 8)
        wt[(size_t)(bx + ty + i) * K + by + tx] = f2bf(tile[tx][ty + i]);
}

// ---------------------------------------------------------------------------
// bf16 MFMA GEMM (unchanged): A [M][K] bf16, BT [N][K] bf16.
// 64x64 tile, 4 waves (2x2 of 32x32), BK=32.
// ---------------------------------------------------------------------------
__global__ __launch_bounds__(256) void gemm_mfma(
    const short* __restrict__ A, const short* __restrict__ BT,
    const float* __restrict__ bias, float* __restrict__ outf,
    short* __restrict__ outb,
    int M, int N, int K, float alpha, int mode)
{
    __shared__ __align__(16) short As[64][40];
    __shared__ __align__(16) short Bs[64][40];

    const int t   = threadIdx.x;
    const int m0  = blockIdx.y * 64, n0 = blockIdx.x * 64;
    const int lane = t & 63, w = t >> 6;
    const int c16 = lane & 15, g = lane >> 4;
    const int wm  = (w & 1) * 32, wn = (w >> 1) * 32;
    const int lr  = t >> 2, lc = (t & 3) * 8;

    f32x4 acc[2][2] = {};

    for (int k0 = 0; k0 < K; k0 += 32) {
        __syncthreads();
        *(short8*)&As[lr][lc] = *(const short8*)(A  + (size_t)(m0 + lr) * K + k0 + lc);
        *(short8*)&Bs[lr][lc] = *(const short8*)(BT + (size_t)(n0 + lr) * K + k0 + lc);
        __syncthreads();

        short8 af[2], bf[2];
        #pragma unroll
        for (int i = 0; i < 2; i++) {
            af[i] = *(const short8*)&As[wm + i * 16 + c16][g * 8];
            bf[i] = *(const short8*)&Bs[wn + i * 16 + c16][g * 8];
        }
        #pragma unroll
        for (int i = 0; i < 2; i++)
            #pragma unroll
            for (int j = 0; j < 2; j++)
                acc[i][j] = __builtin_amdgcn_mfma_f32_16x16x32_bf16(af[i], bf[j], acc[i][j], 0, 0, 0);
    }

    #pragma unroll
    for (int i = 0; i < 2; i++) {
        #pragma unroll
        for (int j = 0; j < 2; j++) {
            #pragma unroll
            for (int r = 0; r < 4; r++) {
                int m = m0 + wm + i * 16 + g * 4 + r;
                int n = n0 + wn + j * 16 + c16;
                float v = acc[i][j][r] * alpha;
                if (mode == 0) {
                    outf[(size_t)m * N + n] = v + (bias ? bias[n] : 0.0f);
                } else {
                    int bb = m >> 11, l = m & 2047;
                    int hh = n >> 5,  cc = n & 31;
                    if (mode == 1)
                        outb[(((size_t)bb * NH + hh) * QL + l) * CH + cc] = f2bf(v);
                    else
                        outb[(((size_t)bb * NH + hh) * CH + cc) * (size_t)KVL + l] = f2bf(v);
                }
            }
        }
    }
}

// ---------------------------------------------------------------------------
// Flash attention, R7: R6 + bias register double-buffering (full-strip
// prefetch distance, matching K/V). Strip loop unrolled x2 with named
// ping-pong bias buffers (rule #20: no runtime-indexed register arrays).
// Swapped-operand QK^T (S^T fragments): lane (c16,g) reg r = S[q=c16][kv=16tt+4g+r].
// Static-max exp2 softmax (log2e folded into Q projection scale).
// ---------------------------------------------------------------------------
__global__ __launch_bounds__(512) void fattn(
    const short* __restrict__ qbf, const short* __restrict__ kbf,
    const short* __restrict__ vtb, const float* __restrict__ mask,
    const float* __restrict__ bias, short* __restrict__ aob)
{
    __shared__ __align__(16) short Kl[2][KVB * 32];   // 16 KB, swizzled
    __shared__ __align__(16) short Vl[2][32 * KVB];   // 16 KB, swizzled (V^T)
    __shared__ __align__(16) short Pl[8][16 * KVB];   // 32 KB, per-wave, swizzled
    __shared__ __align__(16) float Ml[KVL];           // 8 KB, mask terms

    const int t    = threadIdx.x;
    const int w    = t >> 6;
    const int lane = t & 63;
    const int c16  = lane & 15;
    const int g    = lane >> 4;

    const int q0 = blockIdx.x * QB;
    const int h  = blockIdx.y, b = blockIdx.z;
    const int bh = b * NH + h;

    constexpr float L2E  = 1.4426950408889634f;
    constexpr float MBIG = 1e9f * L2E;                  // mask slope * log2e
    constexpr float MOFF = -(1e9f * L2E) - 40.0f * L2E; // -MBIG - C (static max, exp2 units)

    // per-thread staging addresses (K: [128 kv][32 ch], V^T: [32 ch][128 kv])
    const short* ksrc = kbf + (size_t)bh * KVL * CH + (t >> 2) * CH + (t & 3) * 8;
    const short* vsrc = vtb + (size_t)bh * CH * KVL + (t >> 4) * KVL + (t & 15) * 8;
    const int krow = t >> 2,  kch = t & 3;
    const int kbyte = (krow * 64 + kch * 16) ^ ((krow & 7) << 4);
    const int vrow = t >> 4,  vch = t & 15;
    const int vbyte = (vrow * 256 + vch * 16) ^ ((vrow & 7) << 4);

    short8 kreg = *(const short8*)ksrc;     // prefetch strip 0
    short8 vreg = *(const short8*)vsrc;

    // Q fragment: row q0 + w*16 + c16 (scale * log2e folded in projection)
    short8 qf = *(const short8*)(qbf + ((size_t)bh * QL + q0 + w * 16 + c16) * CH + g * 8);

    // bias row for this lane's q-row (swapped layout: row = c16)
    const float* brow = bias + ((size_t)h * QL + q0 + w * 16 + c16) * KVL;

    // mask terms -> LDS once per block
    {
        float4 mv = *(const float4*)(mask + (size_t)b * KVL + t * 4);
        float4 ml = { fmaf(mv.x, MBIG, MOFF), fmaf(mv.y, MBIG, MOFF),
                      fmaf(mv.z, MBIG, MOFF), fmaf(mv.w, MBIG, MOFF) };
        *(float4*)&Ml[t * 4] = ml;
    }

    // prefetch strip 0 bias into biA
    float4 biA[8], biB[8];
    #pragma unroll
    for (int tt = 0; tt < 8; ++tt)
        biA[tt] = *(const float4*)(brow + tt * 16 + 4 * g);

    f32x4 o0 = {0.f, 0.f, 0.f, 0.f}, o1 = {0.f, 0.f, 0.f, 0.f};
    float l0 = 0.f, l1 = 0.f, l2 = 0.f, l3 = 0.f;

    short* pw = &Pl[w][0];
    const f32x4 zero4 = {0.f, 0.f, 0.f, 0.f};

    // One strip: stage K/V regs -> LDS(BUF); barrier; prefetch next K/V regs
    // and next bias -> BN; QK^T; exp with BI; P-write; drain; PV.
#define STRIP_BODY(IT, BUF, BI, BN)                                            \
    {                                                                          \
        const int kv0 = (IT) * KVB;                                            \
        char* klb = (char*)Kl[BUF];                                            \
        char* vlb = (char*)Vl[BUF];                                            \
        *(short8*)(klb + kbyte) = kreg;                                        \
        *(short8*)(vlb + vbyte) = vreg;                                        \
        __syncthreads();                                                       \
        if ((IT) + 1 < NSTRIP) {                                               \
            kreg = *(const short8*)(ksrc + (size_t)((IT) + 1) * KVB * CH);     \
            vreg = *(const short8*)(vsrc + ((IT) + 1) * KVB);                  \
            _Pragma("unroll")                                                  \
            for (int tt = 0; tt < 8; ++tt)                                     \
                BN[tt] = *(const float4*)(brow + ((IT) + 1) * KVB + tt * 16 + 4 * g); \
        }                                                                      \
        float4 mt4[8];                                                         \
        _Pragma("unroll")                                                      \
        for (int tt = 0; tt < 8; ++tt)                                         \
            mt4[tt] = *(const float4*)&Ml[kv0 + tt * 16 + 4 * g];              \
        f32x4 s[8];                                                            \
        __builtin_amdgcn_s_setprio(1);                                         \
        _Pragma("unroll")                                                      \
        for (int tt = 0; tt < 8; ++tt) {                                       \
            int row  = tt * 16 + c16;                                          \
            int byte = (row * 64 + g * 16) ^ ((row & 7) << 4);                 \
            short8 kf = *(const short8*)(klb + byte);                          \
            s[tt] = __builtin_amdgcn_mfma_f32_16x16x32_bf16(kf, qf, zero4, 0, 0, 0); \
        }                                                                      \
        __builtin_amdgcn_s_setprio(0);                                         \
        _Pragma("unroll")                                                      \
        for (int tt = 0; tt < 8; ++tt) {                                       \
            float p0 = __builtin_amdgcn_exp2f(fmaf(BI[tt].x, L2E, s[tt][0] + mt4[tt].x)); \
            float p1 = __builtin_amdgcn_exp2f(fmaf(BI[tt].y, L2E, s[tt][1] + mt4[tt].y)); \
            float p2 = __builtin_amdgcn_exp2f(fmaf(BI[tt].z, L2E, s[tt][2] + mt4[tt].z)); \
            float p3 = __builtin_amdgcn_exp2f(fmaf(BI[tt].w, L2E, s[tt][3] + mt4[tt].w)); \
            l0 += p0; l1 += p1; l2 += p2; l3 += p3;                            \
            short4v pk = { f2bf(p0), f2bf(p1), f2bf(p2), f2bf(p3) };           \
            int byte = (c16 * 256 + tt * 32 + g * 8) ^ ((c16 & 7) << 4);       \
            *(short4v*)((char*)pw + byte) = pk;                                \
        }                                                                      \
        asm volatile("s_waitcnt lgkmcnt(0)" ::: "memory");                     \
        __builtin_amdgcn_sched_barrier(0);                                     \
        __builtin_amdgcn_s_setprio(1);                                         \
        _Pragma("unroll")                                                      \
        for (int kk = 0; kk < 4; ++kk) {                                       \
            int cb = (kk * 32 + g * 8) * 2;                                    \
            int pb  = (c16 * 256 + cb) ^ ((c16 & 7) << 4);                     \
            short8 pf  = *(const short8*)((const char*)pw + pb);               \
            short8 vf0 = *(const short8*)(vlb + ((c16 * 256 + cb) ^ ((c16 & 7) << 4)));        \
            short8 vf1 = *(const short8*)(vlb + (((16 + c16) * 256 + cb) ^ ((c16 & 7) << 4))); \
            o0 = __builtin_amdgcn_mfma_f32_16x16x32_bf16(pf, vf0, o0, 0, 0, 0);\
            o1 = __builtin_amdgcn_mfma_f32_16x16x32_bf16(pf, vf1, o1, 0, 0, 0);\
        }                                                                      \
        __builtin_amdgcn_s_setprio(0);                                         \
    }

    #pragma unroll 1
    for (int p = 0; p < NSTRIP / 2; ++p) {
        STRIP_BODY(2 * p,     0, biA, biB);   // consume biA, prefetch biB
        STRIP_BODY(2 * p + 1, 1, biB, biA);   // consume biB, prefetch biA
    }
#undef STRIP_BODY

    // ---- finalize: lane holds partial row-sum of q-row c16; reduce over
    //      g-groups (xor 16, 32), then redistribute to O-frag rows ----
    float lsum = (l0 + l1) + (l2 + l3);
    lsum += __shfl_xor(lsum, 16);
    lsum += __shfl_xor(lsum, 32);
    short* aop = aob + ((size_t)b * QL + q0 + w * 16) * DM + h * CH;
    #pragma unroll
    for (int r = 0; r < 4; r++) {
        float inv = 1.0f / __shfl(lsum, 4 * g + r);
        int q = 4 * g + r;
        aop[(size_t)q * DM + c16]      = f2bf(o0[r] * inv);
        aop[(size_t)q * DM + 16 + c16] = f2bf(o1[r] * inv);
    }
}

// ---------------------------------------------------------------------------
extern "C" void kernel_launch(void* const* d_in, const int* in_sizes, int n_in,
                              void* d_out, int out_size, void* d_ws, size_t ws_size,
                              hipStream_t stream)
{
    const float* input_q  = (const float*)d_in[0];
    const float* input_kv = (const float*)d_in[1];
    const float* mask     = (const float*)d_in[2];
    const float* bias     = (const float*)d_in[3];
    const float* w_q      = (const float*)d_in[4];
    const float* w_k      = (const float*)d_in[5];
    const float* w_v      = (const float*)d_in[6];
    const float* w_o      = (const float*)d_in[7];
    const float* b_o      = (const float*)d_in[8];
    float* out = (float*)d_out;

    const size_t TOK  = (size_t)B * QL;            // 8192
    const size_t HEAD = (size_t)B * NH * QL * CH;  // 2,097,152 elems

    short* qbf = (short*)d_ws;          // bf16 Q  head-split       4 MB
    short* kbf = qbf + HEAD;            // bf16 K  head-split       4 MB
    short* vtb = kbf + HEAD;            // bf16 V^T head-split      4 MB
    short* aob = vtb + HEAD;            // bf16 attn out [tok][dm]  4 MB
    short* qx  = aob + HEAD;            // bf16 input_q             4 MB
    short* kvx = qx  + HEAD;            // bf16 input_kv            4 MB
    short* wqT = kvx + HEAD;            // bf16 w_q^T  [N][K]       128 KB
    short* wkT = wqT + CQ * DM;
    short* wvT = wkT + CKV * DM;
    short* woT = wvT + CKV * DM;

    dim3 blk(256);
    // 1/sqrt(32) * log2(e): static-max softmax works in exp2 units
    const float qscale = 0.17677669529663687f * 1.4426950408889634f;

    prep_cvt<<<dim3((TOK * CQ / 8 + 255) / 256), blk, 0, stream>>>(input_q,  qx,  (int)(TOK * CQ / 8));
    prep_cvt<<<dim3((TOK * CKV / 8 + 255) / 256), blk, 0, stream>>>(input_kv, kvx, (int)(TOK * CKV / 8));
    prep_wT<<<dim3(DM / 32, CQ / 32),  blk, 0, stream>>>(w_q, wqT, CQ,  DM);
    prep_wT<<<dim3(DM / 32, CKV / 32), blk, 0, stream>>>(w_k, wkT, CKV, DM);
    prep_wT<<<dim3(DM / 32, CKV / 32), blk, 0, stream>>>(w_v, wvT, CKV, DM);
    prep_wT<<<dim3(CQ / 32, DM / 32),  blk, 0, stream>>>(w_o, woT, DM,  CQ);

    dim3 pgrid(DM / 64, TOK / 64);                 // (4, 128)
    gemm_mfma<<<pgrid, blk, 0, stream>>>(qx,  wqT, nullptr, nullptr, qbf,
                                         (int)TOK, DM, CQ,  qscale, 1);
    gemm_mfma<<<pgrid, blk, 0, stream>>>(kvx, wkT, nullptr, nullptr, kbf,
                                         (int)TOK, DM, CKV, 1.0f, 1);
    gemm_mfma<<<pgrid, blk, 0, stream>>>(kvx, wvT, nullptr, nullptr, vtb,
                                         (int)TOK, DM, CKV, 1.0f, 2);

    fattn<<<dim3(QL / QB, NH, B), dim3(512), 0, stream>>>(qbf, kbf, vtb, mask, bias, aob);

    gemm_mfma<<<dim3(CQ / 64, TOK / 64), blk, 0, stream>>>(aob, woT, b_o, out, nullptr,
                                         (int)TOK, CQ, DM, 1.0f, 0);
}

// Round 8
// 120.638 us; speedup vs baseline: 1.1396x; 1.0867x over previous
//
#include <hip/hip_runtime.h>
#include <hip/hip_bf16.h>
#include <math.h>

#define B    4
#define QL   2048
#define KVL  2048
#define CQ   256
#define CKV  256
#define CH   32
#define NH   8
#define DM   256   // NH*CH
#define QB   128   // q rows per fattn block (4 waves x 32)
#define KVB  128   // kv strip per iteration
#define NSTRIP (KVL / KVB)   // 16

typedef __attribute__((ext_vector_type(8)))  short short8;   // 8 x bf16 (4 VGPR)
typedef __attribute__((ext_vector_type(4)))  float f32x4;
typedef __attribute__((ext_vector_type(16))) float f32x16;
typedef __attribute__((ext_vector_type(4)))  unsigned int u32x4;

static __device__ __forceinline__ short f2bf(float x) {
    __hip_bfloat16 h = __float2bfloat16(x);
    return __builtin_bit_cast(short, h);
}
// pack two f32 -> u32 of 2 bf16 (compiler fuses to v_cvt_pk_bf16_f32, m240)
static __device__ __forceinline__ unsigned int pkbf(float lo, float hi) {
    return (unsigned int)(unsigned short)f2bf(lo) |
           ((unsigned int)(unsigned short)f2bf(hi) << 16);
}

// ---------------------------------------------------------------------------
// prep: fp32 -> bf16 copy (8 elems/thread)
// ---------------------------------------------------------------------------
__global__ __launch_bounds__(256) void prep_cvt(
    const float* __restrict__ src, short* __restrict__ dst, int n8)
{
    int i = blockIdx.x * 256 + threadIdx.x;
    if (i >= n8) return;
    const float4* s = (const float4*)src + (size_t)i * 2;
    float4 a = s[0], b = s[1];
    short8 o = { f2bf(a.x), f2bf(a.y), f2bf(a.z), f2bf(a.w),
                 f2bf(b.x), f2bf(b.y), f2bf(b.z), f2bf(b.w) };
    *((short8*)dst + i) = o;
}

// ---------------------------------------------------------------------------
// prep: W [K][N] fp32 -> W^T [N][K] bf16, 32x32 LDS tiles
// ---------------------------------------------------------------------------
__global__ __launch_bounds__(256) void prep_wT(
    const float* __restrict__ w, short* __restrict__ wt, int K, int N)
{
    __shared__ float tile[32][33];
    const int bx = blockIdx.x * 32;            // n
    const int by = blockIdx.y * 32;            // k
    const int tx = threadIdx.x & 31, ty = threadIdx.x >> 5;
    #pragma unroll
    for (int i = 0; i < 32; i += 8)
        tile[ty + i][tx] = w[(size_t)(by + ty + i) * N + bx + tx];
    __syncthreads();
    #pragma unroll
    for (int i = 0; i < 32; i += 8)
        wt[(size_t)(bx + ty + i) * K + by + tx] = f2bf(tile[tx][ty + i]);
}

// ---------------------------------------------------------------------------
// bf16 MFMA GEMM (unchanged): A [M][K] bf16, BT [N][K] bf16.
// 64x64 tile, 4 waves (2x2 of 32x32), BK=32.
// ---------------------------------------------------------------------------
__global__ __launch_bounds__(256) void gemm_mfma(
    const short* __restrict__ A, const short* __restrict__ BT,
    const float* __restrict__ bias, float* __restrict__ outf,
    short* __restrict__ outb,
    int M, int N, int K, float alpha, int mode)
{
    __shared__ __align__(16) short As[64][40];
    __shared__ __align__(16) short Bs[64][40];

    const int t   = threadIdx.x;
    const int m0  = blockIdx.y * 64, n0 = blockIdx.x * 64;
    const int lane = t & 63, w = t >> 6;
    const int c16 = lane & 15, g = lane >> 4;
    const int wm  = (w & 1) * 32, wn = (w >> 1) * 32;
    const int lr  = t >> 2, lc = (t & 3) * 8;

    f32x4 acc[2][2] = {};

    for (int k0 = 0; k0 < K; k0 += 32) {
        __syncthreads();
        *(short8*)&As[lr][lc] = *(const short8*)(A  + (size_t)(m0 + lr) * K + k0 + lc);
        *(short8*)&Bs[lr][lc] = *(const short8*)(BT + (size_t)(n0 + lr) * K + k0 + lc);
        __syncthreads();

        short8 af[2], bf[2];
        #pragma unroll
        for (int i = 0; i < 2; i++) {
            af[i] = *(const short8*)&As[wm + i * 16 + c16][g * 8];
            bf[i] = *(const short8*)&Bs[wn + i * 16 + c16][g * 8];
        }
        #pragma unroll
        for (int i = 0; i < 2; i++)
            #pragma unroll
            for (int j = 0; j < 2; j++)
                acc[i][j] = __builtin_amdgcn_mfma_f32_16x16x32_bf16(af[i], bf[j], acc[i][j], 0, 0, 0);
    }

    #pragma unroll
    for (int i = 0; i < 2; i++) {
        #pragma unroll
        for (int j = 0; j < 2; j++) {
            #pragma unroll
            for (int r = 0; r < 4; r++) {
                int m = m0 + wm + i * 16 + g * 4 + r;
                int n = n0 + wn + j * 16 + c16;
                float v = acc[i][j][r] * alpha;
                if (mode == 0) {
                    outf[(size_t)m * N + n] = v + (bias ? bias[n] : 0.0f);
                } else {
                    int bb = m >> 11, l = m & 2047;
                    int hh = n >> 5,  cc = n & 31;
                    if (mode == 1)
                        outb[(((size_t)bb * NH + hh) * QL + l) * CH + cc] = f2bf(v);
                    else
                        outb[(((size_t)bb * NH + hh) * CH + cc) * (size_t)KVL + l] = f2bf(v);
                }
            }
        }
    }
}

// ---------------------------------------------------------------------------
// Flash attention, R8: 32x32x16 MFMA (2x FLOP per LDS byte), 4 waves x 32 q.
// Swapped QK^T (D = K·Q^T): lane(hi=lane>>5, l31=lane&31) reg r holds
//   S[kv = 32*sub + (r&3)+8*(r>>2)+4*hi][q = l31]   (m74/m101 D-map)
// A-frag (32x32x16): elem j = A[m=lane&31][k=(lane>>5)*8+j]
// B-frag:            elem j = B[k=(lane>>5)*8+j][n=lane&31]
// P never touches LDS: bf16 pair-pack + v_permlane32_swap_b32 builds the PV
// A-fragment in registers (T12). Static-max exp2 softmax. K/V double-buffered
// in swizzled LDS, one barrier per strip. Mask staged once to LDS.
// ---------------------------------------------------------------------------
__global__ __launch_bounds__(256) void fattn(
    const short* __restrict__ qbf, const short* __restrict__ kbf,
    const short* __restrict__ vtb, const float* __restrict__ mask,
    const float* __restrict__ bias, short* __restrict__ aob)
{
    __shared__ __align__(16) short Kl[2][KVB * 32];   // 16 KB, swizzled [kv][ch]
    __shared__ __align__(16) short Vl[2][32 * KVB];   // 16 KB, swizzled [ch][kv]
    __shared__ __align__(16) float Ml[KVL];           // 8 KB, mask terms

    const int t    = threadIdx.x;
    const int wv   = t >> 6;
    const int lane = t & 63;
    const int l31  = lane & 31;
    const int hi   = lane >> 5;

    const int q0 = blockIdx.x * QB;
    const int h  = blockIdx.y, b = blockIdx.z;
    const int bh = b * NH + h;

    constexpr float L2E  = 1.4426950408889634f;
    constexpr float MBIG = 1e9f * L2E;
    constexpr float MOFF = -(1e9f * L2E) - 40.0f * L2E;  // -MBIG - C

    // ---- Q fragments: q row = q0 + wv*32 + l31; ch = cs*16 + hi*8 + j ----
    const short* qrow = qbf + ((size_t)bh * QL + q0 + wv * 32 + l31) * CH;
    short8 qf0 = *(const short8*)(qrow + hi * 8);
    short8 qf1 = *(const short8*)(qrow + 16 + hi * 8);

    // ---- mask terms -> LDS once per block ----
    {
        const float4* mp = (const float4*)(mask + (size_t)b * KVL) + t * 2;
        float4 m0 = mp[0], m1 = mp[1];
        float4 o0 = { fmaf(m0.x, MBIG, MOFF), fmaf(m0.y, MBIG, MOFF),
                      fmaf(m0.z, MBIG, MOFF), fmaf(m0.w, MBIG, MOFF) };
        float4 o1 = { fmaf(m1.x, MBIG, MOFF), fmaf(m1.y, MBIG, MOFF),
                      fmaf(m1.z, MBIG, MOFF), fmaf(m1.w, MBIG, MOFF) };
        *(float4*)&Ml[t * 8]     = o0;
        *(float4*)&Ml[t * 8 + 4] = o1;
    }

    // ---- staging addresses (K: [128][32] rows 64B; V^T: [32][128] rows 256B) ----
    const int rowK = t >> 1, halfK = t & 1;
    const short* ksrc = kbf + (size_t)bh * KVL * CH + rowK * CH + halfK * 16;
    const int kb0 = (rowK * 64 + halfK * 32)      ^ ((rowK & 7) << 4);
    const int kb1 = (rowK * 64 + halfK * 32 + 16) ^ ((rowK & 7) << 4);
    const int rowV = t >> 3, segV = t & 7;
    const short* vsrc = vtb + (size_t)bh * CH * KVL + rowV * KVL + segV * 16;
    const int vb0 = (rowV * 256 + segV * 32)      ^ ((rowV & 7) << 4);
    const int vb1 = (rowV * 256 + segV * 32 + 16) ^ ((rowV & 7) << 4);

    short8 kr0 = *(const short8*)ksrc;          // prefetch strip 0
    short8 kr1 = *(const short8*)(ksrc + 8);
    short8 vr0 = *(const short8*)vsrc;
    short8 vr1 = *(const short8*)(vsrc + 8);

    // bias row for this lane's q-row
    const float* brow = bias + ((size_t)h * QL + q0 + wv * 32 + l31) * KVL;

    f32x16 O;
    #pragma unroll
    for (int r = 0; r < 16; ++r) O[r] = 0.0f;
    float lp0 = 0.f, lp1 = 0.f, lp2 = 0.f, lp3 = 0.f;

    const f32x16 zero16 = O;

    #pragma unroll 1
    for (int it = 0; it < NSTRIP; ++it) {
        const int kv0 = it * KVB;
        char* klb = (char*)Kl[it & 1];
        char* vlb = (char*)Vl[it & 1];

        // ---- stage prefetched K/V -> LDS, one barrier ----
        *(short8*)(klb + kb0) = kr0;
        *(short8*)(klb + kb1) = kr1;
        *(short8*)(vlb + vb0) = vr0;
        *(short8*)(vlb + vb1) = vr1;
        __syncthreads();   // also covers Ml on first iteration

        // ---- issue next strip's global loads ----
        if (it + 1 < NSTRIP) {
            const short* kn = ksrc + (size_t)(it + 1) * KVB * CH;
            const short* vn = vsrc + (it + 1) * KVB;
            kr0 = *(const short8*)kn;  kr1 = *(const short8*)(kn + 8);
            vr0 = *(const short8*)vn;  vr1 = *(const short8*)(vn + 8);
        }

        #pragma unroll
        for (int sub = 0; sub < 4; ++sub) {
            // ---- bias + mask for this 32-kv subtile ----
            float4 bi[4], mt[4];
            #pragma unroll
            for (int rr = 0; rr < 4; ++rr) {
                bi[rr] = *(const float4*)(brow + kv0 + sub * 32 + rr * 8 + hi * 4);
                mt[rr] = *(const float4*)&Ml[kv0 + sub * 32 + rr * 8 + hi * 4];
            }

            // ---- K fragments: row = sub*32 + l31, ch halves cs=0,1 ----
            const int krow32 = sub * 32 + l31;
            const int kswz   = (krow32 & 7) << 4;
            short8 ka0 = *(const short8*)(klb + ((krow32 * 64 + hi * 16)      ^ kswz));
            short8 ka1 = *(const short8*)(klb + ((krow32 * 64 + 32 + hi * 16) ^ kswz));

            // ---- QK^T: S^T = K · Q^T (accumulate over two 16-ch halves) ----
            __builtin_amdgcn_s_setprio(1);
            f32x16 S = __builtin_amdgcn_mfma_f32_32x32x16_bf16(ka0, qf0, zero16, 0, 0, 0);
            S = __builtin_amdgcn_mfma_f32_32x32x16_bf16(ka1, qf1, S, 0, 0, 0);
            __builtin_amdgcn_s_setprio(0);

            // ---- p = exp2(bias*L2E + S + mt), reg r -> kv (r&3)+8*(r>>2)+4hi ----
            float p[16];
            #pragma unroll
            for (int rr = 0; rr < 4; ++rr) {
                p[4*rr+0] = __builtin_amdgcn_exp2f(fmaf(bi[rr].x, L2E, S[4*rr+0] + mt[rr].x));
                p[4*rr+1] = __builtin_amdgcn_exp2f(fmaf(bi[rr].y, L2E, S[4*rr+1] + mt[rr].y));
                p[4*rr+2] = __builtin_amdgcn_exp2f(fmaf(bi[rr].z, L2E, S[4*rr+2] + mt[rr].z));
                p[4*rr+3] = __builtin_amdgcn_exp2f(fmaf(bi[rr].w, L2E, S[4*rr+3] + mt[rr].w));
            }
            lp0 += p[0] + p[1];   lp1 += p[2] + p[3];
            lp0 += p[4] + p[5];   lp1 += p[6] + p[7];
            lp2 += p[8] + p[9];   lp3 += p[10] + p[11];
            lp2 += p[12] + p[13]; lp3 += p[14] + p[15];

            // ---- pack P + permlane32_swap -> PV A-fragments (in-register) ----
            // swap(X,Y): X' = [X.lo|Y.lo], Y' = [X.hi|Y.hi]
            unsigned int a1 = pkbf(p[0],  p[1]),  a2 = pkbf(p[2],  p[3]);
            unsigned int b1 = pkbf(p[4],  p[5]),  b2 = pkbf(p[6],  p[7]);
            unsigned int c1 = pkbf(p[8],  p[9]),  c2 = pkbf(p[10], p[11]);
            unsigned int d1 = pkbf(p[12], p[13]), d2 = pkbf(p[14], p[15]);
            asm("v_permlane32_swap_b32 %0, %1" : "+v"(a1), "+v"(b1));
            asm("v_permlane32_swap_b32 %0, %1" : "+v"(a2), "+v"(b2));
            asm("v_permlane32_swap_b32 %0, %1" : "+v"(c1), "+v"(d1));
            asm("v_permlane32_swap_b32 %0, %1" : "+v"(c2), "+v"(d2));
            u32x4 f0 = { a1, a2, b1, b2 };   // kv 16*sub*2 + 0..15 (local)
            u32x4 f1 = { c1, c2, d1, d2 };   // kv 16..31
            short8 pf0 = __builtin_bit_cast(short8, f0);
            short8 pf1 = __builtin_bit_cast(short8, f1);

            // ---- V fragments: row = ch = l31; kv = sub*32 + st*16 + hi*8 + j ----
            const int vswz = (l31 & 7) << 4;
            short8 vf0 = *(const short8*)(vlb + ((l31 * 256 + sub * 64 + hi * 16)      ^ vswz));
            short8 vf1 = *(const short8*)(vlb + ((l31 * 256 + sub * 64 + 32 + hi * 16) ^ vswz));

            // ---- PV: O[32q][32ch] += P · V ----
            __builtin_amdgcn_s_setprio(1);
            O = __builtin_amdgcn_mfma_f32_32x32x16_bf16(pf0, vf0, O, 0, 0, 0);
            O = __builtin_amdgcn_mfma_f32_32x32x16_bf16(pf1, vf1, O, 0, 0, 0);
            __builtin_amdgcn_s_setprio(0);
        }
    }

    // ---- finalize: l[q=l31] = own-half partial + other half; normalize ----
    float lp = (lp0 + lp1) + (lp2 + lp3);
    lp += __shfl_xor(lp, 32);
    float linv = 1.0f / lp;                     // lane l31 holds 1/l for q=l31
    short* aop = aob + ((size_t)b * QL + q0 + wv * 32) * DM + h * CH;
    #pragma unroll
    for (int r = 0; r < 16; ++r) {
        int q = (r & 3) + 8 * (r >> 2) + 4 * hi;
        float inv = __shfl(linv, q);
        aop[(size_t)q * DM + l31] = f2bf(O[r] * inv);
    }
}

// ---------------------------------------------------------------------------
extern "C" void kernel_launch(void* const* d_in, const int* in_sizes, int n_in,
                              void* d_out, int out_size, void* d_ws, size_t ws_size,
                              hipStream_t stream)
{
    const float* input_q  = (const float*)d_in[0];
    const float* input_kv = (const float*)d_in[1];
    const float* mask     = (const float*)d_in[2];
    const float* bias     = (const float*)d_in[3];
    const float* w_q      = (const float*)d_in[4];
    const float* w_k      = (const float*)d_in[5];
    const float* w_v      = (const float*)d_in[6];
    const float* w_o      = (const float*)d_in[7];
    const float* b_o      = (const float*)d_in[8];
    float* out = (float*)d_out;

    const size_t TOK  = (size_t)B * QL;            // 8192
    const size_t HEAD = (size_t)B * NH * QL * CH;  // 2,097,152 elems

    short* qbf = (short*)d_ws;          // bf16 Q  head-split       4 MB
    short* kbf = qbf + HEAD;            // bf16 K  head-split       4 MB
    short* vtb = kbf + HEAD;            // bf16 V^T head-split      4 MB
    short* aob = vtb + HEAD;            // bf16 attn out [tok][dm]  4 MB
    short* qx  = aob + HEAD;            // bf16 input_q             4 MB
    short* kvx = qx  + HEAD;            // bf16 input_kv            4 MB
    short* wqT = kvx + HEAD;            // bf16 w_q^T  [N][K]       128 KB
    short* wkT = wqT + CQ * DM;
    short* wvT = wkT + CKV * DM;
    short* woT = wvT + CKV * DM;

    dim3 blk(256);
    // 1/sqrt(32) * log2(e): static-max softmax works in exp2 units
    const float qscale = 0.17677669529663687f * 1.4426950408889634f;

    prep_cvt<<<dim3((TOK * CQ / 8 + 255) / 256), blk, 0, stream>>>(input_q,  qx,  (int)(TOK * CQ / 8));
    prep_cvt<<<dim3((TOK * CKV / 8 + 255) / 256), blk, 0, stream>>>(input_kv, kvx, (int)(TOK * CKV / 8));
    prep_wT<<<dim3(DM / 32, CQ / 32),  blk, 0, stream>>>(w_q, wqT, CQ,  DM);
    prep_wT<<<dim3(DM / 32, CKV / 32), blk, 0, stream>>>(w_k, wkT, CKV, DM);
    prep_wT<<<dim3(DM / 32, CKV / 32), blk, 0, stream>>>(w_v, wvT, CKV, DM);
    prep_wT<<<dim3(CQ / 32, DM / 32),  blk, 0, stream>>>(w_o, woT, DM,  CQ);

    dim3 pgrid(DM / 64, TOK / 64);                 // (4, 128)
    gemm_mfma<<<pgrid, blk, 0, stream>>>(qx,  wqT, nullptr, nullptr, qbf,
                                         (int)TOK, DM, CQ,  qscale, 1);
    gemm_mfma<<<pgrid, blk, 0, stream>>>(kvx, wkT, nullptr, nullptr, kbf,
                                         (int)TOK, DM, CKV, 1.0f, 1);
    gemm_mfma<<<pgrid, blk, 0, stream>>>(kvx, wvT, nullptr, nullptr, vtb,
                                         (int)TOK, DM, CKV, 1.0f, 2);

    fattn<<<dim3(QL / QB, NH, B), dim3(256), 0, stream>>>(qbf, kbf, vtb, mask, bias, aob);

    gemm_mfma<<<dim3(CQ / 64, TOK / 64), blk, 0, stream>>>(aob, woT, b_o, out, nullptr,
                                         (int)TOK, CQ, DM, 1.0f, 0);
}